// Round 5
// baseline (182.612 us; speedup 1.0000x reference)
//
#include <hip/hip_runtime.h>
#include <math.h>

#define BB 4
#define LL 1024
#define EE 512
#define HH 8
#define DD 64
#define MAXREL 512

typedef unsigned short u16;
typedef __attribute__((ext_vector_type(8))) short bf16x8;
typedef __attribute__((ext_vector_type(4))) float f32x4;

__device__ __forceinline__ u16 f2bf(float f) {
    unsigned int u = __float_as_uint(f);
    unsigned int r = (u + 0x7FFFu + ((u >> 16) & 1u)) >> 16;
    return (u16)r;
}
__device__ __forceinline__ float bf2f(u16 b) {
    return __uint_as_float(((unsigned int)b) << 16);
}
__device__ __forceinline__ bf16x8 ldf8_bf(const float* p) {
    const float4 a = *(const float4*)(p);
    const float4 b = *(const float4*)(p + 4);
    bf16x8 r;
    r[0] = (short)f2bf(a.x); r[1] = (short)f2bf(a.y);
    r[2] = (short)f2bf(a.z); r[3] = (short)f2bf(a.w);
    r[4] = (short)f2bf(b.x); r[5] = (short)f2bf(b.y);
    r[6] = (short)f2bf(b.z); r[7] = (short)f2bf(b.w);
    return r;
}

// ---------------- projection via MFMA ----------------
__global__ __launch_bounds__(256) void proj_mfma_kernel(
    const float* __restrict__ q_in, const float* __restrict__ k_in, const float* __restrict__ v_in,
    const float* __restrict__ Wq, const float* __restrict__ bq,
    const float* __restrict__ Wk, const float* __restrict__ bk,
    const float* __restrict__ Wv, const float* __restrict__ bv,
    u16* __restrict__ qb, u16* __restrict__ kb, u16* __restrict__ vtb)
{
    int bh = blockIdx.x; int b = bh >> 3; int h = bh & 7;
    int l0 = blockIdx.y * 64;
    int t = threadIdx.x; int w = t >> 6; int lane = t & 63;
    int lg = lane >> 4, lc = lane & 15;
    int lt = l0 + w * 16;

    bf16x8 wq[4][2], wk[4][2], wv[4][2];
    #pragma unroll
    for (int dt = 0; dt < 4; ++dt)
        #pragma unroll
        for (int kc = 0; kc < 2; ++kc) {
            int d = dt * 16 + lc, ko = kc * 32 + lg * 8;
            wq[dt][kc] = ldf8_bf(Wq + d * DD + ko);
            wk[dt][kc] = ldf8_bf(Wk + d * DD + ko);
            wv[dt][kc] = ldf8_bf(Wv + d * DD + ko);
        }
    size_t xrow = ((size_t)b * LL + lt + lc) * EE + h * DD;
    bf16x8 xq[2], xk[2], xv[2];
    #pragma unroll
    for (int kc = 0; kc < 2; ++kc) {
        int ko = kc * 32 + lg * 8;
        xq[kc] = ldf8_bf(q_in + xrow + ko);
        xk[kc] = ldf8_bf(k_in + xrow + ko);
        xv[kc] = ldf8_bf(v_in + xrow + ko);
    }

    f32x4 aq[4] = {}, ak[4] = {}, av[4] = {};
    #pragma unroll
    for (int dt = 0; dt < 4; ++dt) {
        aq[dt] = __builtin_amdgcn_mfma_f32_16x16x32_bf16(wq[dt][0], xq[0], aq[dt], 0, 0, 0);
        aq[dt] = __builtin_amdgcn_mfma_f32_16x16x32_bf16(wq[dt][1], xq[1], aq[dt], 0, 0, 0);
        ak[dt] = __builtin_amdgcn_mfma_f32_16x16x32_bf16(wk[dt][0], xk[0], ak[dt], 0, 0, 0);
        ak[dt] = __builtin_amdgcn_mfma_f32_16x16x32_bf16(wk[dt][1], xk[1], ak[dt], 0, 0, 0);
        av[dt] = __builtin_amdgcn_mfma_f32_16x16x32_bf16(xv[0], wv[dt][0], av[dt], 0, 0, 0);
        av[dt] = __builtin_amdgcn_mfma_f32_16x16x32_bf16(xv[1], wv[dt][1], av[dt], 0, 0, 0);
    }

    #pragma unroll
    for (int dt = 0; dt < 4; ++dt) {
        u16 tq[4], tk[4], tv[4];
        #pragma unroll
        for (int r = 0; r < 4; ++r) {
            int d = dt * 16 + lg * 4 + r;
            tq[r] = f2bf(aq[dt][r] + bq[d]);
            tk[r] = f2bf(ak[dt][r] + bk[d]);
            tv[r] = f2bf(av[dt][r] + bv[dt * 16 + lc]);
        }
        size_t o = ((size_t)bh * LL + lt + lc) * DD + dt * 16 + lg * 4;
        *(uint2*)&qb[o] = *(uint2*)tq;
        *(uint2*)&kb[o] = *(uint2*)tk;
        size_t ov = ((size_t)bh * DD + dt * 16 + lc) * LL + lt + lg * 4;
        *(uint2*)&vtb[ov] = *(uint2*)tv;
    }
}

// ---------------- prep: padded bf16 rel tables + bf16 Wfc ----------------
__global__ __launch_bounds__(256) void prep_kernel(
    const float* __restrict__ relk, const float* __restrict__ relv, const float* __restrict__ Wfc,
    u16* __restrict__ relk_pad, u16* __restrict__ relvt_pad, u16* __restrict__ wfcb)
{
    int idx = blockIdx.x * 256 + threadIdx.x;   // 1024 blocks -> 262144
    if (idx < 2048 * DD) {
        int r = idx >> 6, d = idx & 63;
        int j = r - 512; j = j < 0 ? 0 : (j > 2 * MAXREL ? 2 * MAXREL : j);
        relk_pad[idx] = f2bf(relk[j * DD + d]);
        int dd = idx >> 11, c = idx & 2047;
        int j2 = c - 512; j2 = j2 < 0 ? 0 : (j2 > 2 * MAXREL ? 2 * MAXREL : j2);
        relvt_pad[idx] = f2bf(relv[j2 * DD + dd]);
    }
    if (idx < EE * EE) wfcb[idx] = f2bf(Wfc[idx]);
}

// ---------------- fused attention: direct-global B-frags, shuffle G-gather ----------------
// grid (B*H, L/32), block 256 (4 waves). Wave (rw,cw): q-rows rbase..+16, k-cols c0a..+32.
__global__ __launch_bounds__(256) void attn_mfma_kernel(
    const u16* __restrict__ qb, const u16* __restrict__ kb, const u16* __restrict__ vtb,
    const int* __restrict__ mask,
    const u16* __restrict__ relk_pad, const u16* __restrict__ relvt_pad,
    u16* __restrict__ attn_out)
{
    __shared__ __align__(16) u16 Ps[32 * 72];    // P[row][k]   (4.5 KB)
    __shared__ __align__(16) u16 Pss[32 * 104];  // P'[row][jj] (6.5 KB), jj=k-row+32
    __shared__ float lred[64];

    int bh = blockIdx.x;
    int b = bh >> 3;
    int q0 = blockIdx.y * 32;
    int t = threadIdx.x;
    int lane = t & 63;
    int w = t >> 6;
    int rw = w & 1, cw = w >> 1;
    int rbase = rw * 16;
    int c0a = cw * 32;
    int lg = lane >> 4;
    int lc = lane & 15;
    const size_t bhL = (size_t)bh * LL;

    // zero Pss once: valid window [32-row, 96-row) is rewritten every chunk, rest stays 0
    for (int i = t; i < 416; i += 256) ((uint4*)Pss)[i] = make_uint4(0, 0, 0, 0);

    const u16* qrow = qb + (bhL + q0 + rbase + lc) * DD;
    bf16x8 qf0 = *(const bf16x8*)&qrow[lg * 8];
    bf16x8 qf1 = *(const bf16x8*)&qrow[32 + lg * 8];

    const u16* kb_bh = kb + bhL * DD;
    const u16* vt_bh = vtb + (size_t)bh * DD * LL;
    const int* mk_b = mask + b * LL;

    f32x4 o_acc0 = {0.f, 0.f, 0.f, 0.f};
    f32x4 o_acc1 = {0.f, 0.f, 0.f, 0.f};
    float lacc[4] = {0.f, 0.f, 0.f, 0.f};
    int delta0 = lc - lg * 4;          // per-r: delta = delta0 - r

    __syncthreads();

    for (int k0 = 0; k0 < LL; k0 += 64) {
        int gbase = k0 - q0 + 992 + c0a - rbase + 16;  // rel-K pad row for local jl=0
        int vbase = k0 - q0 + 992;                     // rel-Vt pad col for jj=0

        // ---- scores S = Q.K^T (B-frags direct from global) ----
        const u16* kr0 = kb_bh + (size_t)(k0 + c0a + lc) * DD;
        const u16* kr1 = kr0 + 16 * DD;
        f32x4 s0 = {0.f,0.f,0.f,0.f}, s1 = {0.f,0.f,0.f,0.f};
        s0 = __builtin_amdgcn_mfma_f32_16x16x32_bf16(qf0, *(const bf16x8*)&kr0[lg*8], s0, 0,0,0);
        s0 = __builtin_amdgcn_mfma_f32_16x16x32_bf16(qf1, *(const bf16x8*)&kr0[32+lg*8], s0, 0,0,0);
        s1 = __builtin_amdgcn_mfma_f32_16x16x32_bf16(qf0, *(const bf16x8*)&kr1[lg*8], s1, 0,0,0);
        s1 = __builtin_amdgcn_mfma_f32_16x16x32_bf16(qf1, *(const bf16x8*)&kr1[32+lg*8], s1, 0,0,0);

        // ---- G = Q.RelK^T over this wave's own 48-col window ----
        const u16* gr0 = relk_pad + (size_t)(gbase + lc) * DD;
        const u16* gr1 = gr0 + 16 * DD;
        const u16* gr2 = gr0 + 32 * DD;
        f32x4 g0 = {0.f,0.f,0.f,0.f}, g1 = {0.f,0.f,0.f,0.f}, g2 = {0.f,0.f,0.f,0.f};
        g0 = __builtin_amdgcn_mfma_f32_16x16x32_bf16(qf0, *(const bf16x8*)&gr0[lg*8], g0, 0,0,0);
        g0 = __builtin_amdgcn_mfma_f32_16x16x32_bf16(qf1, *(const bf16x8*)&gr0[32+lg*8], g0, 0,0,0);
        g1 = __builtin_amdgcn_mfma_f32_16x16x32_bf16(qf0, *(const bf16x8*)&gr1[lg*8], g1, 0,0,0);
        g1 = __builtin_amdgcn_mfma_f32_16x16x32_bf16(qf1, *(const bf16x8*)&gr1[32+lg*8], g1, 0,0,0);
        g2 = __builtin_amdgcn_mfma_f32_16x16x32_bf16(qf0, *(const bf16x8*)&gr2[lg*8], g2, 0,0,0);
        g2 = __builtin_amdgcn_mfma_f32_16x16x32_bf16(qf1, *(const bf16x8*)&gr2[32+lg*8], g2, 0,0,0);

        float mb0 = (mk_b[k0 + c0a + lc] != 0) ? 0.f : -1e20f;
        float mb1 = (mk_b[k0 + c0a + 16 + lc] != 0) ? 0.f : -1e20f;

        // ---- diagonal G gather via shuffle + softmax ----
        u16 pb[8];
        #pragma unroll
        for (int r = 0; r < 4; ++r) {
            int d = delta0 - r;
            int src = (lane & 48) | (d & 15);
            float a0 = __shfl(g0[r], src, 64);
            float a1 = __shfl(g1[r], src, 64);
            float a2 = __shfl(g2[r], src, 64);
            float gv0 = (d >= 0) ? a1 : a0;
            float gv1 = (d >= 0) ? a2 : a1;
            float p0 = __expf((s0[r] + mb0 + gv0) * 0.125f);
            float p1 = __expf((s1[r] + mb1 + gv1) * 0.125f);
            u16 pb0 = f2bf(p0), pb1 = f2bf(p1);
            lacc[r] += bf2f(pb0) + bf2f(pb1);
            pb[r] = pb0; pb[4 + r] = pb1;
        }

        __syncthreads();   // prev chunk's PV reads of Ps/Pss complete
        #pragma unroll
        for (int r = 0; r < 4; ++r) {
            int row = rbase + lg * 4 + r;
            int col0 = c0a + lc, col1 = c0a + 16 + lc;
            Ps[row * 72 + col0] = pb[r];
            Ps[row * 72 + col1] = pb[4 + r];
            Pss[row * 104 + col0 - row + 32] = pb[r];
            Pss[row * 104 + col1 - row + 32] = pb[4 + r];
        }
        __syncthreads();   // P visible to all waves

        // ---- PV + rel-V (A-frags from LDS, B-frags from global) ----
        int prow = rbase + lc;
        bf16x8 pa0 = *(const bf16x8*)&Ps[prow * 72 + lg * 8];
        bf16x8 pa1 = *(const bf16x8*)&Ps[prow * 72 + 32 + lg * 8];
        bf16x8 pq0 = *(const bf16x8*)&Pss[prow * 104 + lg * 8];
        bf16x8 pq1 = *(const bf16x8*)&Pss[prow * 104 + 32 + lg * 8];
        bf16x8 pq2 = *(const bf16x8*)&Pss[prow * 104 + 64 + lg * 8];

        const u16* vr0 = vt_bh + (size_t)(c0a + lc) * LL + k0;
        const u16* vr1 = vr0 + 16 * LL;
        const u16* rv0 = relvt_pad + (size_t)(c0a + lc) * 2048 + vbase;
        const u16* rv1 = rv0 + 16 * 2048;

        o_acc0 = __builtin_amdgcn_mfma_f32_16x16x32_bf16(pa0, *(const bf16x8*)&vr0[lg*8], o_acc0, 0,0,0);
        o_acc0 = __builtin_amdgcn_mfma_f32_16x16x32_bf16(pa1, *(const bf16x8*)&vr0[32+lg*8], o_acc0, 0,0,0);
        o_acc0 = __builtin_amdgcn_mfma_f32_16x16x32_bf16(pq0, *(const bf16x8*)&rv0[lg*8], o_acc0, 0,0,0);
        o_acc0 = __builtin_amdgcn_mfma_f32_16x16x32_bf16(pq1, *(const bf16x8*)&rv0[32+lg*8], o_acc0, 0,0,0);
        o_acc0 = __builtin_amdgcn_mfma_f32_16x16x32_bf16(pq2, *(const bf16x8*)&rv0[64+lg*8], o_acc0, 0,0,0);

        o_acc1 = __builtin_amdgcn_mfma_f32_16x16x32_bf16(pa0, *(const bf16x8*)&vr1[lg*8], o_acc1, 0,0,0);
        o_acc1 = __builtin_amdgcn_mfma_f32_16x16x32_bf16(pa1, *(const bf16x8*)&vr1[32+lg*8], o_acc1, 0,0,0);
        o_acc1 = __builtin_amdgcn_mfma_f32_16x16x32_bf16(pq0, *(const bf16x8*)&rv1[lg*8], o_acc1, 0,0,0);
        o_acc1 = __builtin_amdgcn_mfma_f32_16x16x32_bf16(pq1, *(const bf16x8*)&rv1[32+lg*8], o_acc1, 0,0,0);
        o_acc1 = __builtin_amdgcn_mfma_f32_16x16x32_bf16(pq2, *(const bf16x8*)&rv1[64+lg*8], o_acc1, 0,0,0);
    }
    __syncthreads();

    #pragma unroll
    for (int m = 1; m <= 8; m <<= 1) {
        #pragma unroll
        for (int r = 0; r < 4; ++r) lacc[r] += __shfl_xor(lacc[r], m);
    }
    if (lc == 0) {
        #pragma unroll
        for (int r = 0; r < 4; ++r) lred[cw * 32 + rbase + lg * 4 + r] = lacc[r];
    }
    __syncthreads();
    float inv[4];
    #pragma unroll
    for (int r = 0; r < 4; ++r) {
        int row = rbase + lg * 4 + r;
        inv[r] = 1.0f / (lred[row] + lred[32 + row]);
    }
    #pragma unroll
    for (int ct = 0; ct < 2; ++ct) {
        f32x4 ov = ct ? o_acc1 : o_acc0;
        int d = c0a + ct * 16 + lc;
        #pragma unroll
        for (int r = 0; r < 4; ++r) {
            int row = rbase + lg * 4 + r;
            attn_out[((size_t)b * LL + q0 + row) * EE + (bh & 7) * DD + d] = f2bf(ov[r] * inv[r]);
        }
    }
}

// ---------------- final FC via MFMA: out = X @ Wfc.T + bfc ----------------
__global__ __launch_bounds__(256) void fc_mfma_kernel(
    const u16* __restrict__ Xb, const u16* __restrict__ Wb,
    const float* __restrict__ bfc, float* __restrict__ out)
{
    __shared__ u16 As[128][72];
    __shared__ u16 Bs[128][72];
    int m0 = blockIdx.x * 128, n0 = blockIdx.y * 128;
    int t = threadIdx.x, lane = t & 63, w = t >> 6;
    int rw = w & 1, cw = w >> 1;
    int lg = lane >> 4, lc = lane & 15;
    f32x4 acc[4][4] = {};

    for (int kt = 0; kt < EE; kt += 64) {
        __syncthreads();
        #pragma unroll
        for (int i = 0; i < 4; ++i) {
            int unit = i * 256 + t;
            int row = unit >> 3, s = unit & 7;
            *(uint4*)&As[row][s * 8] = *(const uint4*)&Xb[(size_t)(m0 + row) * EE + kt + s * 8];
            *(uint4*)&Bs[row][s * 8] = *(const uint4*)&Wb[(size_t)(n0 + row) * EE + kt + s * 8];
        }
        __syncthreads();
        #pragma unroll
        for (int kc = 0; kc < 2; ++kc) {
            bf16x8 af[4], bf[4];
            #pragma unroll
            for (int i = 0; i < 4; ++i) {
                af[i] = *(const bf16x8*)&As[rw * 64 + i * 16 + lc][kc * 32 + lg * 8];
                bf[i] = *(const bf16x8*)&Bs[cw * 64 + i * 16 + lc][kc * 32 + lg * 8];
            }
            #pragma unroll
            for (int mi = 0; mi < 4; ++mi)
                #pragma unroll
                for (int ni = 0; ni < 4; ++ni)
                    acc[mi][ni] = __builtin_amdgcn_mfma_f32_16x16x32_bf16(af[mi], bf[ni], acc[mi][ni], 0, 0, 0);
        }
    }
    #pragma unroll
    for (int mi = 0; mi < 4; ++mi) {
        #pragma unroll
        for (int ni = 0; ni < 4; ++ni) {
            int n = n0 + cw * 64 + ni * 16 + lc;
            float bias = bfc[n];
            #pragma unroll
            for (int r = 0; r < 4; ++r) {
                int m = m0 + rw * 64 + mi * 16 + lg * 4 + r;
                out[(size_t)m * EE + n] = acc[mi][ni][r] + bias;
            }
        }
    }
}

extern "C" void kernel_launch(void* const* d_in, const int* in_sizes, int n_in,
                              void* d_out, int out_size, void* d_ws, size_t ws_size,
                              hipStream_t stream) {
    const float* query = (const float*)d_in[0];
    const float* key   = (const float*)d_in[1];
    const float* value = (const float*)d_in[2];
    const int*   mask  = (const int*)d_in[3];
    const float* Wq  = (const float*)d_in[4];
    const float* bq  = (const float*)d_in[5];
    const float* Wk  = (const float*)d_in[6];
    const float* bk  = (const float*)d_in[7];
    const float* Wv  = (const float*)d_in[8];
    const float* bv  = (const float*)d_in[9];
    const float* Wfc = (const float*)d_in[10];
    const float* bfc = (const float*)d_in[11];
    const float* relk = (const float*)d_in[12];
    const float* relv = (const float*)d_in[13];
    float* out = (float*)d_out;

    char* ws = (char*)d_ws;
    u16* qb        = (u16*)(ws);                            // 4 MB
    u16* kb        = (u16*)(ws + (4u << 20));               // 4 MB
    u16* vtb       = (u16*)(ws + (8u << 20));               // 4 MB
    u16* attnb     = (u16*)(ws + (12u << 20));              // 4 MB
    u16* relk_pad  = (u16*)(ws + (16u << 20));              // 256 KB
    u16* relvt_pad = (u16*)(ws + (16u << 20) + 262144);     // 256 KB
    u16* wfcb      = (u16*)(ws + (16u << 20) + 524288);     // 512 KB

    proj_mfma_kernel<<<dim3(BB * HH, LL / 64), 256, 0, stream>>>(
        query, key, value, Wq, bq, Wk, bk, Wv, bv, qb, kb, vtb);
    prep_kernel<<<1024, 256, 0, stream>>>(relk, relv, Wfc, relk_pad, relvt_pad, wfcb);
    attn_mfma_kernel<<<dim3(BB * HH, LL / 32), 256, 0, stream>>>(
        qb, kb, vtb, mask, relk_pad, relvt_pad, attnb);
    fc_mfma_kernel<<<dim3(BB * LL / 128, EE / 128), 256, 0, stream>>>(attnb, wfcb, bfc, out);
}